// Round 11
// baseline (424.748 us; speedup 1.0000x reference)
//
#include <hip/hip_runtime.h>

// Problem constants (match the reference).
#define NG 32768
#define MP 8192
#define BG_VAL (-1.0f)
#define MAX_SCALE 0.02f

#define HALF_LOG2E 0.72134752044448170f   // 0.5*log2(e)
#define LOG2E      1.44269504088896340f

// Spatial grid over p-space [0,1]^3.
#define NC 4
#define NCELL 64
#define CELLW 0.25f
#define INV_CELLW 4.0f
// Cutoff: exp2-arg < -45 dropped => d > RADF * sigma_max, RADF = sqrt(45/c).
// sigma_max <= 0.02 (tanh clamp) => R <= 0.158. Error in num/den <= 3e4*2^-45.
#define RADF 7.899f

// Sliced binning (see round 9/10): per cell, gaussian range cut into NSG
// slices, each compacting GATHERED coefficients into a dense subslab;
// points into NSP subslabs. Deterministic ballot compaction, no atomics.
#define NSG 32
#define SCG 256                 // cap/slice (expect ~78, +20 sigma)
#define GCAP (NSG * SCG)        // 8192
#define NSP 4
#define SCP 96                  // cap/slice (expect ~32, +11 sigma)
#define PCAP (NSP * SCP)        // 384

// Persistent-kernel geometry: 512 blocks x 256 threads. launch_bounds(256,2)
// caps VGPR at 128 -> >=4 blocks/CU capacity = 1024 slots >= 512 blocks, so
// ALL blocks are co-resident and the device-wide barrier cannot deadlock.
#define NBLK 512
#define NTHR 256
#define NWAVE (NBLK * (NTHR / 64))   // 2048

#define GJOBS (NCELL * NSG)          // 2048 gaussian bin jobs
#define PJOBS (NCELL * NSP)          // 256 point bin jobs
#define MJOBS (NCELL * (PCAP / 128) * NSG)   // 6144 main jobs

__device__ __forceinline__ float fast_rcp(float x)  { return __builtin_amdgcn_rcpf(x); }
__device__ __forceinline__ float fast_exp2(float x) { return __builtin_amdgcn_exp2f(x); }
__device__ __forceinline__ float fast_exp(float x)  { return fast_exp2(x * LOG2E); }
__device__ __forceinline__ float fast_sigmoid(float x) { return fast_rcp(1.0f + fast_exp(-x)); }

// Device-wide sense barrier: one atomic per block. ctl must be zeroed by the
// preceding zero-kernel (d_ws is poisoned 0xAA by the harness each call).
__device__ __forceinline__ void gbar(int* cnt, int* flag)
{
    __syncthreads();
    if (threadIdx.x == 0) {
        __threadfence();
        int v = __hip_atomic_fetch_add(cnt, 1, __ATOMIC_ACQ_REL, __HIP_MEMORY_SCOPE_AGENT);
        if (v == NBLK - 1) {
            __hip_atomic_store(flag, 1, __ATOMIC_RELEASE, __HIP_MEMORY_SCOPE_AGENT);
        } else {
            while (__hip_atomic_load(flag, __ATOMIC_ACQUIRE, __HIP_MEMORY_SCOPE_AGENT) == 0)
                __builtin_amdgcn_s_sleep(2);
        }
        __threadfence();
    }
    __syncthreads();
}

// K0: zero the barrier state (6 ints) — must be a separate prior dispatch.
__global__ __launch_bounds__(64) void vegs_zero(int* __restrict__ ctl)
{
    if (threadIdx.x < 8) ctl[threadIdx.x] = 0;
}

// ---------------------------------------------------------------------------
// The persistent mega-kernel: build -> bin -> cellmain -> reduce.
// ---------------------------------------------------------------------------
__global__ __launch_bounds__(NTHR, 2) void vegs_mega(
    const float* __restrict__ x,
    const float* __restrict__ xyz,
    const float* __restrict__ weight_raw,
    const float* __restrict__ scaling_raw,
    const float* __restrict__ rotation_raw,
    const float* __restrict__ values_raw,
    float* __restrict__ out,
    float4* __restrict__ gp,
    float4* __restrict__ gr,
    float4* __restrict__ cslab,
    float4* __restrict__ spt,
    int* __restrict__ gcount,
    int* __restrict__ pcount,
    float2* __restrict__ partial,
    int* __restrict__ ctl)
{
    const int tid  = blockIdx.x * NTHR + threadIdx.x;
    const int wid  = (blockIdx.x * (NTHR / 64)) + (threadIdx.x >> 6);
    const int lane = threadIdx.x & 63;

    // ---------------- phase 1: per-gaussian coefficients ----------------
    // A0 = (-c*G00, -c*G11, -c*G22, -2c*G01)
    // A1 = (-2c*G02, -2c*G12, h0, h1)      h = 2c*G*mu
    // A2 = (h2, k0, w, w*v)                k0 = -(h.mu)/2
    if (tid < NG) {
        const int n = tid;
        float s0 = fast_exp(scaling_raw[n * 3 + 0]);
        float s1 = fast_exp(scaling_raw[n * 3 + 1]);
        float s2 = fast_exp(scaling_raw[n * 3 + 2]);
        float r = sqrtf(s0 * s0 + s1 * s1 + s2 * s2) + 1e-8f;
        // tanh(y) = (E-1)/(E+1), E = exp(2y)
        float y = r * (1.0f / MAX_SCALE);
        float E = fast_exp2(2.0f * LOG2E * y);
        float th = (E - 1.0f) * fast_rcp(E + 1.0f);
        float k = (MAX_SCALE * th) * fast_rcp(r);
        s0 *= k; s1 *= k; s2 *= k;

        float i0 = fast_rcp(s0 * s0);
        float i1 = fast_rcp(s1 * s1);
        float i2 = fast_rcp(s2 * s2);

        float qw = rotation_raw[n * 4 + 0];
        float qx = rotation_raw[n * 4 + 1];
        float qy = rotation_raw[n * 4 + 2];
        float qz = rotation_raw[n * 4 + 3];
        float qn = sqrtf(qw * qw + qx * qx + qy * qy + qz * qz) + 1e-12f;
        float iq = fast_rcp(qn);
        qw *= iq; qx *= iq; qy *= iq; qz *= iq;

        float r00 = 1.0f - 2.0f * (qy * qy + qz * qz);
        float r01 = 2.0f * (qx * qy - qw * qz);
        float r02 = 2.0f * (qx * qz + qw * qy);
        float r10 = 2.0f * (qx * qy + qw * qz);
        float r11 = 1.0f - 2.0f * (qx * qx + qz * qz);
        float r12 = 2.0f * (qy * qz - qw * qx);
        float r20 = 2.0f * (qx * qz - qw * qy);
        float r21 = 2.0f * (qy * qz + qw * qx);
        float r22 = 1.0f - 2.0f * (qx * qx + qy * qy);

        float G00 = r00 * r00 * i0 + r01 * r01 * i1 + r02 * r02 * i2;
        float G11 = r10 * r10 * i0 + r11 * r11 * i1 + r12 * r12 * i2;
        float G22 = r20 * r20 * i0 + r21 * r21 * i1 + r22 * r22 * i2;
        float G01 = r00 * r10 * i0 + r01 * r11 * i1 + r02 * r12 * i2;
        float G02 = r00 * r20 * i0 + r01 * r21 * i1 + r02 * r22 * i2;
        float G12 = r10 * r20 * i0 + r11 * r21 * i1 + r12 * r22 * i2;

        float w  = fast_sigmoid(weight_raw[n]);
        float v  = fast_sigmoid(values_raw[n]);
        float m0 = xyz[n * 3 + 0];
        float m1 = xyz[n * 3 + 1];
        float m2 = xyz[n * 3 + 2];

        const float cc = HALF_LOG2E;
        float h0 = 2.0f * cc * (G00 * m0 + G01 * m1 + G02 * m2);
        float h1 = 2.0f * cc * (G01 * m0 + G11 * m1 + G12 * m2);
        float h2 = 2.0f * cc * (G02 * m0 + G12 * m1 + G22 * m2);
        float k0 = -0.5f * (h0 * m0 + h1 * m1 + h2 * m2);

        gp[n * 3 + 0] = make_float4(-cc * G00, -cc * G11, -cc * G22, -2.0f * cc * G01);
        gp[n * 3 + 1] = make_float4(-2.0f * cc * G02, -2.0f * cc * G12, h0, h1);
        gp[n * 3 + 2] = make_float4(h2, k0, w, w * v);

        float smax = fmaxf(s0, fmaxf(s1, s2));
        gr[n] = make_float4(m0, m1, m2, RADF * smax);
    }

    gbar(&ctl[0], &ctl[3]);

    // ---------------- phase 2: sliced binning (per-wave jobs) ----------------
    for (int job = wid; job < GJOBS + PJOBS; job += NWAVE) {
        if (job < GJOBS) {
            const int c = job / NSG;
            const int s = job - c * NSG;
            const int cx = c & 3, cy = (c >> 2) & 3, cz = c >> 4;
            const float lo0 = cx * CELLW, hi0 = lo0 + CELLW;
            const float lo1 = cy * CELLW, hi1 = lo1 + CELLW;
            const float lo2 = cz * CELLW, hi2 = lo2 + CELLW;
            float4* __restrict__ slab = cslab + ((size_t)c * GCAP + s * SCG) * 3;

            const int beg = s * (NG / NSG);
            const int end = beg + (NG / NSG);
            int cnt = 0;
            #pragma unroll 4
            for (int base = beg; base < end; base += 64) {
                const int gid = base + lane;
                float4 g = gr[gid];
                float dx = fmaxf(fmaxf(lo0 - g.x, g.x - hi0), 0.0f);
                float dy = fmaxf(fmaxf(lo1 - g.y, g.y - hi1), 0.0f);
                float dz = fmaxf(fmaxf(lo2 - g.z, g.z - hi2), 0.0f);
                bool hit = (dx * dx + dy * dy + dz * dz) <= g.w * g.w;
                unsigned long long mask = __ballot(hit);
                int pos = cnt + __popcll(mask & ((1ULL << lane) - 1ULL));
                if (hit && pos < SCG) {
                    slab[pos * 3 + 0] = gp[gid * 3 + 0];
                    slab[pos * 3 + 1] = gp[gid * 3 + 1];
                    slab[pos * 3 + 2] = gp[gid * 3 + 2];
                }
                cnt += __popcll(mask);
            }
            if (lane == 0) gcount[job] = min(cnt, SCG);
        } else {
            const int pb = job - GJOBS;
            const int c = pb / NSP;
            const int s = pb - c * NSP;
            float4* __restrict__ slab = spt + (size_t)c * PCAP + s * SCP;

            const int beg = s * (MP / NSP);
            const int end = beg + (MP / NSP);
            int cnt = 0;
            #pragma unroll 4
            for (int base = beg; base < end; base += 64) {
                const int m = base + lane;
                float p0 = (x[m * 3 + 0] + 1.0f) * 0.5f;
                float p1 = (x[m * 3 + 1] + 1.0f) * 0.5f;
                float p2 = (x[m * 3 + 2] + 1.0f) * 0.5f;
                int cx = min(NC - 1, max(0, (int)(p0 * INV_CELLW)));
                int cy = min(NC - 1, max(0, (int)(p1 * INV_CELLW)));
                int cz = min(NC - 1, max(0, (int)(p2 * INV_CELLW)));
                bool hit = (cx + NC * (cy + NC * cz)) == c;
                unsigned long long mask = __ballot(hit);
                int pos = cnt + __popcll(mask & ((1ULL << lane) - 1ULL));
                if (hit && pos < SCP)
                    slab[pos] = make_float4(p0, p1, p2, __int_as_float(m));
                cnt += __popcll(mask);
            }
            if (lane == 0) pcount[pb] = min(cnt, SCP);
        }
    }

    gbar(&ctl[1], &ctl[4]);

    // ---------------- phase 3: pair evaluation (per-wave jobs) ----------------
    for (int job = wid; job < MJOBS; job += NWAVE) {
        const int c  = job / ((PCAP / 128) * NSG);
        const int r2 = job - c * ((PCAP / 128) * NSG);
        const int pb = r2 / NSG;
        const int k  = r2 - pb * NSG;

        const int n0 = pcount[c * NSP + 0];
        const int n1 = pcount[c * NSP + 1];
        const int n2 = pcount[c * NSP + 2];
        const int n3 = pcount[c * NSP + 3];
        const int c1 = n0, c2 = c1 + n1, c3 = c2 + n2;
        const int nt = c3 + n3;
        if (pb * 128 >= nt) continue;       // wave-uniform skip

        const int  piA  = pb * 128 + lane;
        const int  piB  = piA + 64;
        const bool actA = piA < nt;
        const bool actB = piB < nt;
        const int  peA  = actA ? piA : 0;
        const int  peB  = actB ? piB : 0;

        int sA = (peA >= c1) + (peA >= c2) + (peA >= c3);
        int cumA = (sA == 0) ? 0 : ((sA == 1) ? c1 : ((sA == 2) ? c2 : c3));
        int sB = (peB >= c1) + (peB >= c2) + (peB >= c3);
        int cumB = (sB == 0) ? 0 : ((sB == 1) ? c1 : ((sB == 2) ? c2 : c3));

        float4 PA = spt[c * PCAP + sA * SCP + (peA - cumA)];
        float4 PB = spt[c * PCAP + sB * SCP + (peB - cumB)];
        const float a0 = PA.x, a1 = PA.y, a2 = PA.z;
        const float b0 = PB.x, b1 = PB.y, b2 = PB.z;

        const float4* __restrict__ base = cslab + ((size_t)c * GCAP + k * SCG) * 3;
        const int glen = gcount[c * NSG + k];

        float numA = 0.0f, denA = 0.0f;
        float numB = 0.0f, denB = 0.0f;

        #pragma unroll 4
        for (int j = 0; j < glen; ++j) {
            float4 A0 = base[j * 3 + 0];
            float4 A1 = base[j * 3 + 1];
            float4 A2 = base[j * 3 + 2];

            float t0 = fmaf(A0.x, a0, A1.z);
            t0 = fmaf(A0.w, a1, t0);
            t0 = fmaf(A1.x, a2, t0);
            float t1 = fmaf(A0.y, a1, A1.w);
            t1 = fmaf(A1.y, a2, t1);
            float t2 = fmaf(A0.z, a2, A2.x);
            float qA = fmaf(a0, t0, A2.y);
            qA = fmaf(a1, t1, qA);
            qA = fmaf(a2, t2, qA);
            float eA = fast_exp2(qA);
            denA = fmaf(A2.z, eA, denA);
            numA = fmaf(A2.w, eA, numA);

            float u0 = fmaf(A0.x, b0, A1.z);
            u0 = fmaf(A0.w, b1, u0);
            u0 = fmaf(A1.x, b2, u0);
            float u1 = fmaf(A0.y, b1, A1.w);
            u1 = fmaf(A1.y, b2, u1);
            float u2 = fmaf(A0.z, b2, A2.x);
            float qB = fmaf(b0, u0, A2.y);
            qB = fmaf(b1, u1, qB);
            qB = fmaf(b2, u2, qB);
            float eB = fast_exp2(qB);
            denB = fmaf(A2.z, eB, denB);
            numB = fmaf(A2.w, eB, numB);
        }

        if (actA) partial[(size_t)k * (NCELL * PCAP) + c * PCAP + piA] = make_float2(numA, denA);
        if (actB) partial[(size_t)k * (NCELL * PCAP) + c * PCAP + piB] = make_float2(numB, denB);
    }

    gbar(&ctl[2], &ctl[5]);

    // ---------------- phase 4: reduce + select + scatter ----------------
    if (tid < NCELL * PCAP) {
        const int g  = tid;
        const int c  = g / PCAP;
        const int pi = g - c * PCAP;

        const int n0 = pcount[c * NSP + 0];
        const int n1 = pcount[c * NSP + 1];
        const int n2 = pcount[c * NSP + 2];
        const int n3 = pcount[c * NSP + 3];
        const int c1 = n0, c2 = c1 + n1, c3 = c2 + n2;
        const int nt = c3 + n3;
        if (pi < nt) {
            float num = 0.0f, den = 0.0f;
            #pragma unroll 8
            for (int k = 0; k < NSG; ++k) {
                float2 p = partial[(size_t)k * (NCELL * PCAP) + g];
                num += p.x;
                den += p.y;
            }
            int s = (pi >= c1) + (pi >= c2) + (pi >= c3);
            int cum = (s == 0) ? 0 : ((s == 1) ? c1 : ((s == 2) ? c2 : c3));
            int orig = __float_as_int(spt[c * PCAP + s * SCP + (pi - cum)].w);
            out[orig] = (den > 1e-8f) ? num : BG_VAL;
        }
    }
}

extern "C" void kernel_launch(void* const* d_in, const int* in_sizes, int n_in,
                              void* d_out, int out_size, void* d_ws, size_t ws_size,
                              hipStream_t stream) {
    const float* x            = (const float*)d_in[0];
    const float* xyz          = (const float*)d_in[1];
    const float* weight_raw   = (const float*)d_in[2];
    const float* scaling_raw  = (const float*)d_in[3];
    const float* rotation_raw = (const float*)d_in[4];
    const float* values_raw   = (const float*)d_in[5];
    float* out = (float*)d_out;

    // workspace layout (~32.5 MB of the 256 MB ws)
    char* ws = (char*)d_ws;
    size_t off = 0;
    float4* gp    = (float4*)(ws + off); off += (size_t)NG * 3 * sizeof(float4);            // 1.5 MB
    float4* gr    = (float4*)(ws + off); off += (size_t)NG * sizeof(float4);                // 512 KB
    float4* spt   = (float4*)(ws + off); off += (size_t)NCELL * PCAP * sizeof(float4);      // 384 KB
    float4* cslab = (float4*)(ws + off); off += (size_t)NCELL * GCAP * 3 * sizeof(float4);  // 24 MB
    float2* partial = (float2*)(ws + off); off += (size_t)NSG * NCELL * PCAP * sizeof(float2); // 6 MB
    int* gcount = (int*)(ws + off); off += (size_t)NCELL * NSG * sizeof(int);
    int* pcount = (int*)(ws + off); off += (size_t)NCELL * NSP * sizeof(int);
    int* ctl    = (int*)(ws + off); off += 64 * sizeof(int);

    vegs_zero<<<1, 64, 0, stream>>>(ctl);

    vegs_mega<<<NBLK, NTHR, 0, stream>>>(
        x, xyz, weight_raw, scaling_raw, rotation_raw, values_raw, out,
        gp, gr, cslab, spt, gcount, pcount, partial, ctl);
}

// Round 12
// 104.717 us; speedup vs baseline: 4.0561x; 4.0561x over previous
//
#include <hip/hip_runtime.h>

// Problem constants (match the reference).
#define NG 32768
#define MP 8192
#define BG_VAL (-1.0f)
#define MAX_SCALE 0.02f

#define HALF_LOG2E 0.72134752044448170f   // 0.5*log2(e)
#define LOG2E      1.44269504088896340f

// Spatial grid over p-space [0,1]^3.
#define NC 4
#define NCELL 64
#define CELLW 0.25f
#define INV_CELLW 4.0f
// Cutoff: exp2-arg < -45 dropped => d > RADF * sigma_max, RADF = sqrt(45/c).
// sigma_max <= 0.02 (tanh clamp) => R <= 0.158. Error in num/den <= 3e4*2^-45.
#define RADF 7.899f

// Sliced binning: per cell, gaussian range cut into NSG slices, each wave
// compacting GATHERED coefficients (recomputed in-place from raw inputs)
// into a dense subslab; points into NSP subslabs. Ballot compaction,
// no atomics, deterministic.
#define NSG 32
#define SCG 256                 // cap/slice (expect ~78, +20 sigma)
#define GCAP (NSG * SCG)        // 8192
#define NSP 4
#define SCP 96                  // cap/slice (expect ~32, +11 sigma)
#define PCAP (NSP * SCP)        // 384

#define GJOBS (NCELL * NSG)     // 2048
#define PJOBS (NCELL * NSP)     // 256

__device__ __forceinline__ float fast_rcp(float x)  { return __builtin_amdgcn_rcpf(x); }
__device__ __forceinline__ float fast_exp2(float x) { return __builtin_amdgcn_exp2f(x); }
__device__ __forceinline__ float fast_exp(float x)  { return fast_exp2(x * LOG2E); }
__device__ __forceinline__ float fast_sigmoid(float x) { return fast_rcp(1.0f + fast_exp(-x)); }

// ---------------------------------------------------------------------------
// K1: fused build+bin. blocks [0, GJOBS): wave (c,s) scans its 1024-gaussian
// candidate range; computes the soft-clamped radius from scaling_raw only;
// hit lanes additionally compute the full polynomial coefficients and write
// them (ballot-compacted) into the cell's dense subslab. blocks
// [GJOBS, +PJOBS): point slices, read from x.
// Coefficients (c = 0.5*log2e), alpha = w * exp2(poly(p)):
//   A0 = (-c*G00, -c*G11, -c*G22, -2c*G01)
//   A1 = (-2c*G02, -2c*G12, h0, h1)      h = 2c*G*mu
//   A2 = (h2, k0, w, w*v)                k0 = -(h.mu)/2
// ---------------------------------------------------------------------------
__global__ __launch_bounds__(64) void vegs_bin(
    const float* __restrict__ x,
    const float* __restrict__ xyz,
    const float* __restrict__ weight_raw,
    const float* __restrict__ scaling_raw,
    const float* __restrict__ rotation_raw,
    const float* __restrict__ values_raw,
    float4* __restrict__ cslab,
    float4* __restrict__ spt,
    int* __restrict__ gcount,
    int* __restrict__ pcount)
{
    const int bid  = blockIdx.x;
    const int lane = threadIdx.x;

    if (bid < GJOBS) {
        const int c = bid / NSG;
        const int s = bid - c * NSG;
        const int cx = c & 3, cy = (c >> 2) & 3, cz = c >> 4;
        const float lo0 = cx * CELLW, hi0 = lo0 + CELLW;
        const float lo1 = cy * CELLW, hi1 = lo1 + CELLW;
        const float lo2 = cz * CELLW, hi2 = lo2 + CELLW;
        float4* __restrict__ slab = cslab + ((size_t)c * GCAP + s * SCG) * 3;

        const int beg = s * (NG / NSG);
        const int end = beg + (NG / NSG);
        int cnt = 0;
        #pragma unroll 2
        for (int base = beg; base < end; base += 64) {
            const int n = base + lane;

            // radius from scaling only
            float s0 = fast_exp(scaling_raw[n * 3 + 0]);
            float s1 = fast_exp(scaling_raw[n * 3 + 1]);
            float s2 = fast_exp(scaling_raw[n * 3 + 2]);
            float r = sqrtf(s0 * s0 + s1 * s1 + s2 * s2) + 1e-8f;
            // tanh(y) = (E-1)/(E+1), E = exp(2y)
            float y = r * (1.0f / MAX_SCALE);
            float E = fast_exp2(2.0f * LOG2E * y);
            float th = (E - 1.0f) * fast_rcp(E + 1.0f);
            float kk = (MAX_SCALE * th) * fast_rcp(r);
            s0 *= kk; s1 *= kk; s2 *= kk;

            float m0 = xyz[n * 3 + 0];
            float m1 = xyz[n * 3 + 1];
            float m2 = xyz[n * 3 + 2];

            float R = RADF * fmaxf(s0, fmaxf(s1, s2));
            float dx = fmaxf(fmaxf(lo0 - m0, m0 - hi0), 0.0f);
            float dy = fmaxf(fmaxf(lo1 - m1, m1 - hi1), 0.0f);
            float dz = fmaxf(fmaxf(lo2 - m2, m2 - hi2), 0.0f);
            bool hit = (dx * dx + dy * dy + dz * dz) <= R * R;

            unsigned long long mask = __ballot(hit);
            int pos = cnt + __popcll(mask & ((1ULL << lane) - 1ULL));

            if (hit && pos < SCG) {
                // full coefficient computation (hit lanes only)
                float i0 = fast_rcp(s0 * s0);
                float i1 = fast_rcp(s1 * s1);
                float i2 = fast_rcp(s2 * s2);

                float qw = rotation_raw[n * 4 + 0];
                float qx = rotation_raw[n * 4 + 1];
                float qy = rotation_raw[n * 4 + 2];
                float qz = rotation_raw[n * 4 + 3];
                float qn = sqrtf(qw * qw + qx * qx + qy * qy + qz * qz) + 1e-12f;
                float iq = fast_rcp(qn);
                qw *= iq; qx *= iq; qy *= iq; qz *= iq;

                float r00 = 1.0f - 2.0f * (qy * qy + qz * qz);
                float r01 = 2.0f * (qx * qy - qw * qz);
                float r02 = 2.0f * (qx * qz + qw * qy);
                float r10 = 2.0f * (qx * qy + qw * qz);
                float r11 = 1.0f - 2.0f * (qx * qx + qz * qz);
                float r12 = 2.0f * (qy * qz - qw * qx);
                float r20 = 2.0f * (qx * qz - qw * qy);
                float r21 = 2.0f * (qy * qz + qw * qx);
                float r22 = 1.0f - 2.0f * (qx * qx + qy * qy);

                float G00 = r00 * r00 * i0 + r01 * r01 * i1 + r02 * r02 * i2;
                float G11 = r10 * r10 * i0 + r11 * r11 * i1 + r12 * r12 * i2;
                float G22 = r20 * r20 * i0 + r21 * r21 * i1 + r22 * r22 * i2;
                float G01 = r00 * r10 * i0 + r01 * r11 * i1 + r02 * r12 * i2;
                float G02 = r00 * r20 * i0 + r01 * r21 * i1 + r02 * r22 * i2;
                float G12 = r10 * r20 * i0 + r11 * r21 * i1 + r12 * r22 * i2;

                float w  = fast_sigmoid(weight_raw[n]);
                float v  = fast_sigmoid(values_raw[n]);

                const float cc = HALF_LOG2E;
                float h0 = 2.0f * cc * (G00 * m0 + G01 * m1 + G02 * m2);
                float h1 = 2.0f * cc * (G01 * m0 + G11 * m1 + G12 * m2);
                float h2 = 2.0f * cc * (G02 * m0 + G12 * m1 + G22 * m2);
                float k0 = -0.5f * (h0 * m0 + h1 * m1 + h2 * m2);

                slab[pos * 3 + 0] = make_float4(-cc * G00, -cc * G11, -cc * G22, -2.0f * cc * G01);
                slab[pos * 3 + 1] = make_float4(-2.0f * cc * G02, -2.0f * cc * G12, h0, h1);
                slab[pos * 3 + 2] = make_float4(h2, k0, w, w * v);
            }
            cnt += __popcll(mask);
        }
        if (lane == 0) gcount[bid] = min(cnt, SCG);
    } else {
        const int pb = bid - GJOBS;
        const int c = pb / NSP;
        const int s = pb - c * NSP;
        float4* __restrict__ slab = spt + (size_t)c * PCAP + s * SCP;

        const int beg = s * (MP / NSP);
        const int end = beg + (MP / NSP);
        int cnt = 0;
        #pragma unroll 4
        for (int base = beg; base < end; base += 64) {
            const int m = base + lane;
            float p0 = (x[m * 3 + 0] + 1.0f) * 0.5f;
            float p1 = (x[m * 3 + 1] + 1.0f) * 0.5f;
            float p2 = (x[m * 3 + 2] + 1.0f) * 0.5f;
            int cx = min(NC - 1, max(0, (int)(p0 * INV_CELLW)));
            int cy = min(NC - 1, max(0, (int)(p1 * INV_CELLW)));
            int cz = min(NC - 1, max(0, (int)(p2 * INV_CELLW)));
            bool hit = (cx + NC * (cy + NC * cz)) == c;
            unsigned long long mask = __ballot(hit);
            int pos = cnt + __popcll(mask & ((1ULL << lane) - 1ULL));
            if (hit && pos < SCP)
                slab[pos] = make_float4(p0, p1, p2, __int_as_float(m));
            cnt += __popcll(mask);
        }
        if (lane == 0) pcount[pb] = min(cnt, SCP);
    }
}

// ---------------------------------------------------------------------------
// K2: main. grid = (NCELL, PCAP/128, NSG), 64 threads, 2 points/lane over the
// UNION of the cell's point subslabs (prefix over pcount). Coefficients
// streamed from the dense slab: 3 contiguous wave-uniform float4 loads/pair.
// Per pair: 9-fma Horner + exp2 + 2 accum fmas.
// ---------------------------------------------------------------------------
__global__ __launch_bounds__(64) void vegs_cellmain(
    const float4* __restrict__ cslab,
    const float4* __restrict__ spt,
    const int* __restrict__ gcount,
    const int* __restrict__ pcount,
    float2* __restrict__ partial)
{
    const int c    = blockIdx.x;
    const int pb   = blockIdx.y;
    const int k    = blockIdx.z;
    const int lane = threadIdx.x;

    const int n0 = pcount[c * NSP + 0];
    const int n1 = pcount[c * NSP + 1];
    const int n2 = pcount[c * NSP + 2];
    const int n3 = pcount[c * NSP + 3];
    const int c1 = n0, c2 = c1 + n1, c3 = c2 + n2;
    const int nt = c3 + n3;
    if (pb * 128 >= nt) return;             // block-uniform exit

    const int  piA  = pb * 128 + lane;
    const int  piB  = piA + 64;
    const bool actA = piA < nt;
    const bool actB = piB < nt;
    const int  peA  = actA ? piA : 0;
    const int  peB  = actB ? piB : 0;

    int sA = (peA >= c1) + (peA >= c2) + (peA >= c3);
    int cumA = (sA == 0) ? 0 : ((sA == 1) ? c1 : ((sA == 2) ? c2 : c3));
    int sB = (peB >= c1) + (peB >= c2) + (peB >= c3);
    int cumB = (sB == 0) ? 0 : ((sB == 1) ? c1 : ((sB == 2) ? c2 : c3));

    float4 PA = spt[c * PCAP + sA * SCP + (peA - cumA)];
    float4 PB = spt[c * PCAP + sB * SCP + (peB - cumB)];
    const float a0 = PA.x, a1 = PA.y, a2 = PA.z;
    const float b0 = PB.x, b1 = PB.y, b2 = PB.z;

    const float4* __restrict__ base = cslab + ((size_t)c * GCAP + k * SCG) * 3;
    const int glen = gcount[c * NSG + k];

    float numA = 0.0f, denA = 0.0f;
    float numB = 0.0f, denB = 0.0f;

    #pragma unroll 4
    for (int j = 0; j < glen; ++j) {
        float4 A0 = base[j * 3 + 0];
        float4 A1 = base[j * 3 + 1];
        float4 A2 = base[j * 3 + 2];

        // point A
        float t0 = fmaf(A0.x, a0, A1.z);
        t0 = fmaf(A0.w, a1, t0);
        t0 = fmaf(A1.x, a2, t0);
        float t1 = fmaf(A0.y, a1, A1.w);
        t1 = fmaf(A1.y, a2, t1);
        float t2 = fmaf(A0.z, a2, A2.x);
        float qA = fmaf(a0, t0, A2.y);
        qA = fmaf(a1, t1, qA);
        qA = fmaf(a2, t2, qA);
        float eA = fast_exp2(qA);
        denA = fmaf(A2.z, eA, denA);
        numA = fmaf(A2.w, eA, numA);

        // point B
        float u0 = fmaf(A0.x, b0, A1.z);
        u0 = fmaf(A0.w, b1, u0);
        u0 = fmaf(A1.x, b2, u0);
        float u1 = fmaf(A0.y, b1, A1.w);
        u1 = fmaf(A1.y, b2, u1);
        float u2 = fmaf(A0.z, b2, A2.x);
        float qB = fmaf(b0, u0, A2.y);
        qB = fmaf(b1, u1, qB);
        qB = fmaf(b2, u2, qB);
        float eB = fast_exp2(qB);
        denB = fmaf(A2.z, eB, denB);
        numB = fmaf(A2.w, eB, numB);
    }

    if (actA) partial[(size_t)k * (NCELL * PCAP) + c * PCAP + piA] = make_float2(numA, denA);
    if (actB) partial[(size_t)k * (NCELL * PCAP) + c * PCAP + piB] = make_float2(numB, denB);
}

// ---------------------------------------------------------------------------
// K3: reduce gaussian-slices, background select, scatter to original order.
// ---------------------------------------------------------------------------
__global__ __launch_bounds__(256) void vegs_reduce(
    const float2* __restrict__ partial,
    const float4* __restrict__ spt,
    const int* __restrict__ pcount,
    float* __restrict__ out)
{
    const int g  = blockIdx.x * 256 + threadIdx.x;   // 0 .. NCELL*PCAP-1
    const int c  = g / PCAP;
    const int pi = g - c * PCAP;

    const int n0 = pcount[c * NSP + 0];
    const int n1 = pcount[c * NSP + 1];
    const int n2 = pcount[c * NSP + 2];
    const int n3 = pcount[c * NSP + 3];
    const int c1 = n0, c2 = c1 + n1, c3 = c2 + n2;
    const int nt = c3 + n3;
    if (pi >= nt) return;

    float num = 0.0f, den = 0.0f;
    #pragma unroll 8
    for (int k = 0; k < NSG; ++k) {
        float2 p = partial[(size_t)k * (NCELL * PCAP) + g];
        num += p.x;
        den += p.y;
    }

    int s = (pi >= c1) + (pi >= c2) + (pi >= c3);
    int cum = (s == 0) ? 0 : ((s == 1) ? c1 : ((s == 2) ? c2 : c3));
    int orig = __float_as_int(spt[c * PCAP + s * SCP + (pi - cum)].w);
    out[orig] = (den > 1e-8f) ? num : BG_VAL;
}

extern "C" void kernel_launch(void* const* d_in, const int* in_sizes, int n_in,
                              void* d_out, int out_size, void* d_ws, size_t ws_size,
                              hipStream_t stream) {
    const float* x            = (const float*)d_in[0];
    const float* xyz          = (const float*)d_in[1];
    const float* weight_raw   = (const float*)d_in[2];
    const float* scaling_raw  = (const float*)d_in[3];
    const float* rotation_raw = (const float*)d_in[4];
    const float* values_raw   = (const float*)d_in[5];
    float* out = (float*)d_out;

    // workspace layout (~30.5 MB of the 256 MB ws)
    char* ws = (char*)d_ws;
    size_t off = 0;
    float4* spt   = (float4*)(ws + off); off += (size_t)NCELL * PCAP * sizeof(float4);      // 384 KB
    float4* cslab = (float4*)(ws + off); off += (size_t)NCELL * GCAP * 3 * sizeof(float4);  // 24 MB
    float2* partial = (float2*)(ws + off); off += (size_t)NSG * NCELL * PCAP * sizeof(float2); // 6 MB
    int* gcount = (int*)(ws + off); off += (size_t)NCELL * NSG * sizeof(int);
    int* pcount = (int*)(ws + off); off += (size_t)NCELL * NSP * sizeof(int);

    vegs_bin<<<GJOBS + PJOBS, 64, 0, stream>>>(
        x, xyz, weight_raw, scaling_raw, rotation_raw, values_raw,
        cslab, spt, gcount, pcount);

    dim3 mg(NCELL, PCAP / 128, NSG);
    vegs_cellmain<<<mg, 64, 0, stream>>>(cslab, spt, gcount, pcount, partial);

    vegs_reduce<<<NCELL * PCAP / 256, 256, 0, stream>>>(partial, spt, pcount, out);
}

// Round 13
// 98.949 us; speedup vs baseline: 4.2926x; 1.0583x over previous
//
#include <hip/hip_runtime.h>

// Problem constants (match the reference).
#define NG 32768
#define MP 8192
#define BG_VAL (-1.0f)
#define MAX_SCALE 0.02f

#define HALF_LOG2E 0.72134752044448170f   // 0.5*log2(e)
#define LOG2E      1.44269504088896340f

// Spatial grid over p-space [0,1]^3.
#define NC 4
#define NCELL 64
#define CELLW 0.25f
#define INV_CELLW 4.0f
// Cutoff: exp2-arg < -45 dropped => d > RADF * sigma_max, RADF = sqrt(45/c).
// sigma_max <= 0.02 (tanh clamp) => R <= 0.158. Error in num/den <= 3e4*2^-45.
#define RADF 7.899f

// Sliced binning: per cell, gaussian range cut into NSG slices, each wave
// compacting GATHERED coefficients (recomputed in-place from raw inputs)
// into a dense subslab; points into NSP subslabs. Ballot compaction,
// no atomics, deterministic.
#define NSG 32
#define SCG 256                 // cap/slice (expect ~78, +20 sigma)
#define GCAP (NSG * SCG)        // 8192
#define NSP 4
#define SCP 96                  // cap/slice (expect ~32, +11 sigma)
#define PCAP (NSP * SCP)        // 384

#define GJOBS (NCELL * NSG)     // 2048
#define PJOBS (NCELL * NSP)     // 256

__device__ __forceinline__ float fast_rcp(float x)  { return __builtin_amdgcn_rcpf(x); }
__device__ __forceinline__ float fast_exp2(float x) { return __builtin_amdgcn_exp2f(x); }
__device__ __forceinline__ float fast_exp(float x)  { return fast_exp2(x * LOG2E); }
__device__ __forceinline__ float fast_sigmoid(float x) { return fast_rcp(1.0f + fast_exp(-x)); }

// ---------------------------------------------------------------------------
// K1: fused build+bin (unchanged from round 12 — measured fine).
// Coefficients (c = 0.5*log2e), alpha = w * exp2(poly(p)):
//   A0 = (-c*G00, -c*G11, -c*G22, -2c*G01)
//   A1 = (-2c*G02, -2c*G12, h0, h1)      h = 2c*G*mu
//   A2 = (h2, k0, w, w*v)                k0 = -(h.mu)/2
// ---------------------------------------------------------------------------
__global__ __launch_bounds__(64) void vegs_bin(
    const float* __restrict__ x,
    const float* __restrict__ xyz,
    const float* __restrict__ weight_raw,
    const float* __restrict__ scaling_raw,
    const float* __restrict__ rotation_raw,
    const float* __restrict__ values_raw,
    float4* __restrict__ cslab,
    float4* __restrict__ spt,
    int* __restrict__ gcount,
    int* __restrict__ pcount)
{
    const int bid  = blockIdx.x;
    const int lane = threadIdx.x;

    if (bid < GJOBS) {
        const int c = bid / NSG;
        const int s = bid - c * NSG;
        const int cx = c & 3, cy = (c >> 2) & 3, cz = c >> 4;
        const float lo0 = cx * CELLW, hi0 = lo0 + CELLW;
        const float lo1 = cy * CELLW, hi1 = lo1 + CELLW;
        const float lo2 = cz * CELLW, hi2 = lo2 + CELLW;
        float4* __restrict__ slab = cslab + ((size_t)c * GCAP + s * SCG) * 3;

        const int beg = s * (NG / NSG);
        const int end = beg + (NG / NSG);
        int cnt = 0;
        #pragma unroll 2
        for (int base = beg; base < end; base += 64) {
            const int n = base + lane;

            // radius from scaling only
            float s0 = fast_exp(scaling_raw[n * 3 + 0]);
            float s1 = fast_exp(scaling_raw[n * 3 + 1]);
            float s2 = fast_exp(scaling_raw[n * 3 + 2]);
            float r = sqrtf(s0 * s0 + s1 * s1 + s2 * s2) + 1e-8f;
            // tanh(y) = (E-1)/(E+1), E = exp(2y)
            float y = r * (1.0f / MAX_SCALE);
            float E = fast_exp2(2.0f * LOG2E * y);
            float th = (E - 1.0f) * fast_rcp(E + 1.0f);
            float kk = (MAX_SCALE * th) * fast_rcp(r);
            s0 *= kk; s1 *= kk; s2 *= kk;

            float m0 = xyz[n * 3 + 0];
            float m1 = xyz[n * 3 + 1];
            float m2 = xyz[n * 3 + 2];

            float R = RADF * fmaxf(s0, fmaxf(s1, s2));
            float dx = fmaxf(fmaxf(lo0 - m0, m0 - hi0), 0.0f);
            float dy = fmaxf(fmaxf(lo1 - m1, m1 - hi1), 0.0f);
            float dz = fmaxf(fmaxf(lo2 - m2, m2 - hi2), 0.0f);
            bool hit = (dx * dx + dy * dy + dz * dz) <= R * R;

            unsigned long long mask = __ballot(hit);
            int pos = cnt + __popcll(mask & ((1ULL << lane) - 1ULL));

            if (hit && pos < SCG) {
                float i0 = fast_rcp(s0 * s0);
                float i1 = fast_rcp(s1 * s1);
                float i2 = fast_rcp(s2 * s2);

                float qw = rotation_raw[n * 4 + 0];
                float qx = rotation_raw[n * 4 + 1];
                float qy = rotation_raw[n * 4 + 2];
                float qz = rotation_raw[n * 4 + 3];
                float qn = sqrtf(qw * qw + qx * qx + qy * qy + qz * qz) + 1e-12f;
                float iq = fast_rcp(qn);
                qw *= iq; qx *= iq; qy *= iq; qz *= iq;

                float r00 = 1.0f - 2.0f * (qy * qy + qz * qz);
                float r01 = 2.0f * (qx * qy - qw * qz);
                float r02 = 2.0f * (qx * qz + qw * qy);
                float r10 = 2.0f * (qx * qy + qw * qz);
                float r11 = 1.0f - 2.0f * (qx * qx + qz * qz);
                float r12 = 2.0f * (qy * qz - qw * qx);
                float r20 = 2.0f * (qx * qz - qw * qy);
                float r21 = 2.0f * (qy * qz + qw * qx);
                float r22 = 1.0f - 2.0f * (qx * qx + qy * qy);

                float G00 = r00 * r00 * i0 + r01 * r01 * i1 + r02 * r02 * i2;
                float G11 = r10 * r10 * i0 + r11 * r11 * i1 + r12 * r12 * i2;
                float G22 = r20 * r20 * i0 + r21 * r21 * i1 + r22 * r22 * i2;
                float G01 = r00 * r10 * i0 + r01 * r11 * i1 + r02 * r12 * i2;
                float G02 = r00 * r20 * i0 + r01 * r21 * i1 + r02 * r22 * i2;
                float G12 = r10 * r20 * i0 + r11 * r21 * i1 + r12 * r22 * i2;

                float w  = fast_sigmoid(weight_raw[n]);
                float v  = fast_sigmoid(values_raw[n]);

                const float cc = HALF_LOG2E;
                float h0 = 2.0f * cc * (G00 * m0 + G01 * m1 + G02 * m2);
                float h1 = 2.0f * cc * (G01 * m0 + G11 * m1 + G12 * m2);
                float h2 = 2.0f * cc * (G02 * m0 + G12 * m1 + G22 * m2);
                float k0 = -0.5f * (h0 * m0 + h1 * m1 + h2 * m2);

                slab[pos * 3 + 0] = make_float4(-cc * G00, -cc * G11, -cc * G22, -2.0f * cc * G01);
                slab[pos * 3 + 1] = make_float4(-2.0f * cc * G02, -2.0f * cc * G12, h0, h1);
                slab[pos * 3 + 2] = make_float4(h2, k0, w, w * v);
            }
            cnt += __popcll(mask);
        }
        if (lane == 0) gcount[bid] = min(cnt, SCG);
    } else {
        const int pb = bid - GJOBS;
        const int c = pb / NSP;
        const int s = pb - c * NSP;
        float4* __restrict__ slab = spt + (size_t)c * PCAP + s * SCP;

        const int beg = s * (MP / NSP);
        const int end = beg + (MP / NSP);
        int cnt = 0;
        #pragma unroll 4
        for (int base = beg; base < end; base += 64) {
            const int m = base + lane;
            float p0 = (x[m * 3 + 0] + 1.0f) * 0.5f;
            float p1 = (x[m * 3 + 1] + 1.0f) * 0.5f;
            float p2 = (x[m * 3 + 2] + 1.0f) * 0.5f;
            int cx = min(NC - 1, max(0, (int)(p0 * INV_CELLW)));
            int cy = min(NC - 1, max(0, (int)(p1 * INV_CELLW)));
            int cz = min(NC - 1, max(0, (int)(p2 * INV_CELLW)));
            bool hit = (cx + NC * (cy + NC * cz)) == c;
            unsigned long long mask = __ballot(hit);
            int pos = cnt + __popcll(mask & ((1ULL << lane) - 1ULL));
            if (hit && pos < SCP)
                slab[pos] = make_float4(p0, p1, p2, __int_as_float(m));
            cnt += __popcll(mask);
        }
        if (lane == 0) pcount[pb] = min(cnt, SCP);
    }
}

// ---------------------------------------------------------------------------
// K2: main. grid = (NCELL, PCAP/128, NSG), 64 threads, 2 points/lane.
// NEW: chunked LDS-broadcast staging with register double-buffer —
// lane l vector-loads gaussian (chunk*64+l)'s 3 float4s (coalesced 48 B
// records) into regs, writes to a wave-private LDS buffer (2 alternating
// buffers), prefetches the next chunk, then evaluates 64 broadcast
// ds_read_b128 iterations (uniform address -> conflict-free). This removes
// the wave-uniform global stream (s_load scalar-cache thrash suspect).
// ---------------------------------------------------------------------------
__global__ __launch_bounds__(64) void vegs_cellmain(
    const float4* __restrict__ cslab,
    const float4* __restrict__ spt,
    const int* __restrict__ gcount,
    const int* __restrict__ pcount,
    float2* __restrict__ partial)
{
    __shared__ float4 lds[2][64 * 3];

    const int c    = blockIdx.x;
    const int pb   = blockIdx.y;
    const int k    = blockIdx.z;
    const int lane = threadIdx.x;

    const int n0 = pcount[c * NSP + 0];
    const int n1 = pcount[c * NSP + 1];
    const int n2 = pcount[c * NSP + 2];
    const int n3 = pcount[c * NSP + 3];
    const int c1 = n0, c2 = c1 + n1, c3 = c2 + n2;
    const int nt = c3 + n3;
    if (pb * 128 >= nt) return;             // block-uniform exit

    const int  piA  = pb * 128 + lane;
    const int  piB  = piA + 64;
    const bool actA = piA < nt;
    const bool actB = piB < nt;
    const int  peA  = actA ? piA : 0;
    const int  peB  = actB ? piB : 0;

    int sA = (peA >= c1) + (peA >= c2) + (peA >= c3);
    int cumA = (sA == 0) ? 0 : ((sA == 1) ? c1 : ((sA == 2) ? c2 : c3));
    int sB = (peB >= c1) + (peB >= c2) + (peB >= c3);
    int cumB = (sB == 0) ? 0 : ((sB == 1) ? c1 : ((sB == 2) ? c2 : c3));

    float4 PA = spt[c * PCAP + sA * SCP + (peA - cumA)];
    float4 PB = spt[c * PCAP + sB * SCP + (peB - cumB)];
    const float a0 = PA.x, a1 = PA.y, a2 = PA.z;
    const float b0 = PB.x, b1 = PB.y, b2 = PB.z;

    const float4* __restrict__ slab = cslab + ((size_t)c * GCAP + k * SCG) * 3;
    const int glen = gcount[c * NSG + k];

    float numA = 0.0f, denA = 0.0f;
    float numB = 0.0f, denB = 0.0f;

    // preload chunk 0 into registers (coalesced vector loads)
    float4 r0, r1, r2;
    if (lane < glen) {
        r0 = slab[lane * 3 + 0];
        r1 = slab[lane * 3 + 1];
        r2 = slab[lane * 3 + 2];
    }

    const int nch = (glen + 63) >> 6;
    for (int ch = 0; ch < nch; ++ch) {
        const int cnt = min(glen - (ch << 6), 64);
        float4* buf = lds[ch & 1];

        if (lane < cnt) {
            buf[lane * 3 + 0] = r0;
            buf[lane * 3 + 1] = r1;
            buf[lane * 3 + 2] = r2;
        }
        // prefetch next chunk while this one is processed
        const int nb = ((ch + 1) << 6) + lane;
        if (nb < glen) {
            r0 = slab[nb * 3 + 0];
            r1 = slab[nb * 3 + 1];
            r2 = slab[nb * 3 + 2];
        }

        #pragma unroll 2
        for (int j = 0; j < cnt; ++j) {
            float4 A0 = buf[j * 3 + 0];
            float4 A1 = buf[j * 3 + 1];
            float4 A2 = buf[j * 3 + 2];

            // point A
            float t0 = fmaf(A0.x, a0, A1.z);
            t0 = fmaf(A0.w, a1, t0);
            t0 = fmaf(A1.x, a2, t0);
            float t1 = fmaf(A0.y, a1, A1.w);
            t1 = fmaf(A1.y, a2, t1);
            float t2 = fmaf(A0.z, a2, A2.x);
            float qA = fmaf(a0, t0, A2.y);
            qA = fmaf(a1, t1, qA);
            qA = fmaf(a2, t2, qA);
            float eA = fast_exp2(qA);
            denA = fmaf(A2.z, eA, denA);
            numA = fmaf(A2.w, eA, numA);

            // point B
            float u0 = fmaf(A0.x, b0, A1.z);
            u0 = fmaf(A0.w, b1, u0);
            u0 = fmaf(A1.x, b2, u0);
            float u1 = fmaf(A0.y, b1, A1.w);
            u1 = fmaf(A1.y, b2, u1);
            float u2 = fmaf(A0.z, b2, A2.x);
            float qB = fmaf(b0, u0, A2.y);
            qB = fmaf(b1, u1, qB);
            qB = fmaf(b2, u2, qB);
            float eB = fast_exp2(qB);
            denB = fmaf(A2.z, eB, denB);
            numB = fmaf(A2.w, eB, numB);
        }
    }

    if (actA) partial[(size_t)k * (NCELL * PCAP) + c * PCAP + piA] = make_float2(numA, denA);
    if (actB) partial[(size_t)k * (NCELL * PCAP) + c * PCAP + piB] = make_float2(numB, denB);
}

// ---------------------------------------------------------------------------
// K3: reduce gaussian-slices, background select, scatter to original order.
// ---------------------------------------------------------------------------
__global__ __launch_bounds__(256) void vegs_reduce(
    const float2* __restrict__ partial,
    const float4* __restrict__ spt,
    const int* __restrict__ pcount,
    float* __restrict__ out)
{
    const int g  = blockIdx.x * 256 + threadIdx.x;   // 0 .. NCELL*PCAP-1
    const int c  = g / PCAP;
    const int pi = g - c * PCAP;

    const int n0 = pcount[c * NSP + 0];
    const int n1 = pcount[c * NSP + 1];
    const int n2 = pcount[c * NSP + 2];
    const int n3 = pcount[c * NSP + 3];
    const int c1 = n0, c2 = c1 + n1, c3 = c2 + n2;
    const int nt = c3 + n3;
    if (pi >= nt) return;

    float num = 0.0f, den = 0.0f;
    #pragma unroll 8
    for (int k = 0; k < NSG; ++k) {
        float2 p = partial[(size_t)k * (NCELL * PCAP) + g];
        num += p.x;
        den += p.y;
    }

    int s = (pi >= c1) + (pi >= c2) + (pi >= c3);
    int cum = (s == 0) ? 0 : ((s == 1) ? c1 : ((s == 2) ? c2 : c3));
    int orig = __float_as_int(spt[c * PCAP + s * SCP + (pi - cum)].w);
    out[orig] = (den > 1e-8f) ? num : BG_VAL;
}

extern "C" void kernel_launch(void* const* d_in, const int* in_sizes, int n_in,
                              void* d_out, int out_size, void* d_ws, size_t ws_size,
                              hipStream_t stream) {
    const float* x            = (const float*)d_in[0];
    const float* xyz          = (const float*)d_in[1];
    const float* weight_raw   = (const float*)d_in[2];
    const float* scaling_raw  = (const float*)d_in[3];
    const float* rotation_raw = (const float*)d_in[4];
    const float* values_raw   = (const float*)d_in[5];
    float* out = (float*)d_out;

    // workspace layout (~30.5 MB of the 256 MB ws)
    char* ws = (char*)d_ws;
    size_t off = 0;
    float4* spt   = (float4*)(ws + off); off += (size_t)NCELL * PCAP * sizeof(float4);      // 384 KB
    float4* cslab = (float4*)(ws + off); off += (size_t)NCELL * GCAP * 3 * sizeof(float4);  // 24 MB
    float2* partial = (float2*)(ws + off); off += (size_t)NSG * NCELL * PCAP * sizeof(float2); // 6 MB
    int* gcount = (int*)(ws + off); off += (size_t)NCELL * NSG * sizeof(int);
    int* pcount = (int*)(ws + off); off += (size_t)NCELL * NSP * sizeof(int);

    vegs_bin<<<GJOBS + PJOBS, 64, 0, stream>>>(
        x, xyz, weight_raw, scaling_raw, rotation_raw, values_raw,
        cslab, spt, gcount, pcount);

    dim3 mg(NCELL, PCAP / 128, NSG);
    vegs_cellmain<<<mg, 64, 0, stream>>>(cslab, spt, gcount, pcount, partial);

    vegs_reduce<<<NCELL * PCAP / 256, 256, 0, stream>>>(partial, spt, pcount, out);
}